// Round 6
// baseline (764.877 us; speedup 1.0000x reference)
//
#include <hip/hip_runtime.h>
#include <hip/hip_bf16.h>
#include <cstdint>
#include <cstddef>

#define T_SEQ 4096
#define HID   2048
#define NH    16
#define HD    128
#define QKVN  6144
#define KVB   32

typedef unsigned short u16;
typedef __bf16 bf16x8 __attribute__((ext_vector_type(8)));
typedef float  f32x4  __attribute__((ext_vector_type(4)));

typedef const __attribute__((address_space(1))) void* gas_ptr;
typedef __attribute__((address_space(3))) void* las_ptr;

__device__ __forceinline__ void async16(const void* g, void* l) {
  __builtin_amdgcn_global_load_lds((gas_ptr)g, (las_ptr)l, 16, 0, 0);
}

__device__ __forceinline__ u16 f2bf(float f) {
  unsigned int u = __float_as_uint(f);
  u += 0x7fffu + ((u >> 16) & 1u);
  return (u16)(u >> 16);
}

// ---------------- elementwise cast f32 -> bf16 ----------------
__global__ void cast_f32_bf16(const float* __restrict__ in, u16* __restrict__ out, int n) {
  int i = (blockIdx.x * blockDim.x + threadIdx.x) * 4;
  if (i >= n) return;
  float4 v = *(const float4*)&in[i];
  uint2 o;
  o.x = (unsigned)f2bf(v.x) | ((unsigned)f2bf(v.y) << 16);
  o.y = (unsigned)f2bf(v.z) | ((unsigned)f2bf(v.w) << 16);
  *(uint2*)&out[i] = o;
}

// ---------------- transpose + cast: f32 [R][C] -> bf16 [C][R] ----------------
__global__ void transpose_cast(const float* __restrict__ in, u16* __restrict__ out,
                               int R, int C) {
  __shared__ float tile[64][65];
  int c0 = blockIdx.x * 64, r0 = blockIdx.y * 64;
  int tid = threadIdx.x;
#pragma unroll
  for (int i = 0; i < 16; ++i) {
    int e = i * 256 + tid;
    int rr = e >> 6, cc = e & 63;
    tile[rr][cc] = in[(size_t)(r0 + rr) * C + c0 + cc];
  }
  __syncthreads();
#pragma unroll
  for (int i = 0; i < 16; ++i) {
    int e = i * 256 + tid;
    int oc = e >> 6, orr = e & 63;
    out[(size_t)(c0 + oc) * R + r0 + orr] = f2bf(tile[orr][oc]);
  }
}

// ---------------- GEMM: C[M][N] = A[M][K] * BT[N][K]^T  (bf16 in, f32 out) --------
// 128x128 tile, BK=32, dbuf + counted-vmcnt pipeline, key-swizzled LDS (2-way max).
__global__ __launch_bounds__(256)
void gemm_bf16_bt(const u16* __restrict__ A, const u16* __restrict__ BT,
                  float* __restrict__ C, int M, int N, int K) {
  __shared__ u16 As[2][128 * 32];
  __shared__ u16 Bs[2][128 * 32];
  int tid = threadIdx.x;
  int row0 = blockIdx.y * 128, col0 = blockIdx.x * 128;
  int wv = tid >> 6, lane = tid & 63, lr = lane & 15, lq = lane >> 4;
  int wm = (wv >> 1) * 64, wn = (wv & 1) * 64;
  f32x4 acc[4][4] = {};

  auto stage = [&](int buf, int ks) {
#pragma unroll
    for (int k = 0; k < 2; ++k) {
      int c = k * 256 + tid;            // 512 chunks/matrix; dest lane-linear
      int row = c >> 2, col = c & 3;
      int key = (row & 3) ^ ((row >> 2) & 3);
      async16(&A[(size_t)(row0 + row) * K + ks + (col ^ key) * 8], &As[buf][c * 8]);
      async16(&BT[(size_t)(col0 + row) * K + ks + (col ^ key) * 8], &Bs[buf][c * 8]);
    }
  };

  stage(0, 0);
  int nk = K >> 5;
  for (int t = 0; t < nk; ++t) {
    int cur = t & 1;
    if (t + 1 < nk) {
      stage(cur ^ 1, (t + 1) * 32);
      asm volatile("s_waitcnt vmcnt(4)" ::: "memory");   // tile t done; t+1 in flight
    } else {
      asm volatile("s_waitcnt vmcnt(0)" ::: "memory");
    }
    __builtin_amdgcn_s_barrier();
    __builtin_amdgcn_sched_barrier(0);

    const char* AsB = (const char*)&As[cur][0];
    const char* BsB = (const char*)&Bs[cur][0];
    bf16x8 a[4], b[4];
#pragma unroll
    for (int mi = 0; mi < 4; ++mi) {
      int row = wm + mi * 16 + lr;
      int key = (row & 3) ^ ((row >> 2) & 3);
      a[mi] = *(const bf16x8*)(AsB + row * 64 + ((lq ^ key) << 4));
    }
#pragma unroll
    for (int ni = 0; ni < 4; ++ni) {
      int row = wn + ni * 16 + lr;
      int key = (row & 3) ^ ((row >> 2) & 3);
      b[ni] = *(const bf16x8*)(BsB + row * 64 + ((lq ^ key) << 4));
    }
#pragma unroll
    for (int mi = 0; mi < 4; ++mi)
#pragma unroll
      for (int ni = 0; ni < 4; ++ni)
        acc[mi][ni] = __builtin_amdgcn_mfma_f32_16x16x32_bf16(a[mi], b[ni], acc[mi][ni], 0, 0, 0);

    __builtin_amdgcn_sched_barrier(0);
    __builtin_amdgcn_s_barrier();
  }

#pragma unroll
  for (int mi = 0; mi < 4; ++mi)
#pragma unroll
    for (int ni = 0; ni < 4; ++ni)
#pragma unroll
      for (int r = 0; r < 4; ++r)
        C[(size_t)(row0 + wm + mi * 16 + lq * 4 + r) * N + col0 + wn + ni * 16 + lr] =
            acc[mi][ni][r];
}

// ---------------- RoPE + head-major reorg for Q,K ----------------
// Q pre-scaled by (1/sqrt(HD)) * log2(e) so softmax uses exp2 directly.
#define SCL2 0.12753224f

__global__ void rope_reorg(const float* __restrict__ qkv, const int* __restrict__ pos,
                           u16* __restrict__ Qh, u16* __restrict__ Kh) {
  int idx = blockIdx.x * 256 + threadIdx.x;
  if (idx >= T_SEQ * NH * 64) return;
  int d = idx & 63;
  int h = (idx >> 6) & (NH - 1);
  int t = idx >> 10;
  float p = (float)pos[t];
  float inv = exp2f((float)d * -0.20762050594046932f);
  float f = p * inv;
  float s, c;
  __sincosf(f, &s, &c);

  size_t ib = (size_t)t * QKVN + h * HD + d;
  float q1 = qkv[ib], q2 = qkv[ib + 64];
  float k1 = qkv[ib + HID], k2 = qkv[ib + HID + 64];
  size_t ob = ((size_t)h * T_SEQ + t) * HD + d;
  Qh[ob]      = f2bf((q1 * c - q2 * s) * SCL2);
  Qh[ob + 64] = f2bf((q2 * c + q1 * s) * SCL2);
  Kh[ob]      = f2bf(k1 * c - k2 * s);
  Kh[ob + 64] = f2bf(k2 * c + k1 * s);
}

// ---------------- V transpose: qkv v-part f32 -> Vt bf16 [NH][HD][T] -------------
__global__ void vtrans(const float* __restrict__ qkv, u16* __restrict__ Vt) {
  __shared__ float tile[64][129];
  int t0 = blockIdx.x * 64;
  int h = blockIdx.y;
  int tid = threadIdx.x;
#pragma unroll
  for (int i = 0; i < 32; ++i) {
    int e = i * 256 + tid;
    int tt = e >> 7, d = e & 127;
    tile[tt][d] = qkv[(size_t)(t0 + tt) * QKVN + 2 * HID + h * HD + d];
  }
  __syncthreads();
#pragma unroll
  for (int i = 0; i < 32; ++i) {
    int e = i * 256 + tid;
    int d = e >> 6, tt = e & 63;
    Vt[((size_t)h * HD + d) * T_SEQ + t0 + tt] = f2bf(tile[tt][d]);
  }
}

// ---------------- causal flash attention v6 -------------------------------------
// 4 waves/block, Q-tile 128 (32 rows/wave), KVBLK=32, dbuf + counted-vmcnt
// pipeline (prefetch stays in flight across barriers). K XOR-8 swizzle; V key
// swizzle (2-way = free); P 72B padded rows. Defer-max (T13) + deferred l.
__global__ __launch_bounds__(256)
void attn_fwd(const u16* __restrict__ Qh, const u16* __restrict__ Kh,
              const u16* __restrict__ Vt, u16* __restrict__ attn) {
  __shared__ u16 Ks[2][32 * 128];   // [kv][d] 256B rows, XOR-8 swizzle
  __shared__ u16 Vs[2][128 * 32];   // [d][kv] 64B rows, key swizzle
  __shared__ u16 Ps[4][32 * 36];    // per-wave [q][kv], 72B padded rows

  int tid = threadIdx.x;
  int wv = tid >> 6, lane = tid & 63, lr = lane & 15, lq = lane >> 4;
  // balanced decode: CU-paired blocks get bq and 31-bq
  int id = blockIdx.x;
  int h = id >> 5;
  int bq = (id < 256) ? (id & 31) : 31 - (id & 31);
  int q0 = bq * 128, wrow0 = q0 + wv * 32;
  char* PsB = (char*)&Ps[wv][0];

  // Q fragments (pre-scaled): rows wrow0 + mi*16 + lr, k = kd*32 + lq*8
  bf16x8 qf[2][4];
#pragma unroll
  for (int mi = 0; mi < 2; ++mi)
#pragma unroll
    for (int kd = 0; kd < 4; ++kd)
      qf[mi][kd] = *(const bf16x8*)
          &Qh[((size_t)h * T_SEQ + wrow0 + mi * 16 + lr) * HD + kd * 32 + lq * 8];

  f32x4 acc_o[2][8] = {};
  float m_run[2][4], l_run[2][4];
#pragma unroll
  for (int mi = 0; mi < 2; ++mi)
#pragma unroll
    for (int r = 0; r < 4; ++r) { m_run[mi][r] = -1e30f; l_run[mi][r] = 0.0f; }

  auto stage = [&](int buf, int jb) {
#pragma unroll
    for (int k = 0; k < 2; ++k) {      // K tile: 512 chunks, 16/row, src pre-swz
      int c = k * 256 + tid;
      int row = c >> 4;
      int sc = (c ^ (row & 7)) & 15;
      async16(&Kh[((size_t)h * T_SEQ + jb + row) * HD + sc * 8], &Ks[buf][c * 8]);
    }
#pragma unroll
    for (int k = 0; k < 2; ++k) {      // V tile: 512 chunks, 4/row, key-swz
      int c = k * 256 + tid;
      int row = c >> 2, col = c & 3;
      int key = (row & 3) ^ ((row >> 2) & 3);
      async16(&Vt[((size_t)h * HD + row) * T_SEQ + jb + (col ^ key) * 8],
              &Vs[buf][c * 8]);
    }
  };

  int nt = bq * 4 + 4;
  stage(0, 0);

  for (int j = 0; j < nt; ++j) {
    int cur = j & 1;
    int jb = j * KVB;
    if (j + 1 < nt) {
      stage(cur ^ 1, jb + KVB);
      asm volatile("s_waitcnt vmcnt(4)" ::: "memory");  // j done; j+1 in flight
    } else {
      asm volatile("s_waitcnt vmcnt(0)" ::: "memory");
    }
    __builtin_amdgcn_s_barrier();
    __builtin_amdgcn_sched_barrier(0);

    if (jb <= wrow0 + 31) {
      const char* KsB = (const char*)&Ks[cur][0];
      const char* VsB = (const char*)&Vs[cur][0];

      // ---- S = Q K^T  (32 x 32) ----
      f32x4 s_acc[2][2] = {};
#pragma unroll
      for (int kd = 0; kd < 4; ++kd) {
#pragma unroll
        for (int nj = 0; nj < 2; ++nj) {
          int row = nj * 16 + lr;
          int byt = (row << 8) + kd * 64 + lq * 16;
          bf16x8 kf = *(const bf16x8*)(KsB + (byt ^ ((row & 7) << 4)));
#pragma unroll
          for (int mi = 0; mi < 2; ++mi)
            s_acc[mi][nj] = __builtin_amdgcn_mfma_f32_16x16x32_bf16(
                qf[mi][kd], kf, s_acc[mi][nj], 0, 0, 0);
        }
      }

      // ---- causal mask (wave-uniform branch) ----
      if (jb + KVB - 1 > wrow0) {
#pragma unroll
        for (int mi = 0; mi < 2; ++mi)
#pragma unroll
          for (int r = 0; r < 4; ++r) {
            int qrow = wrow0 + mi * 16 + lq * 4 + r;
#pragma unroll
            for (int nj = 0; nj < 2; ++nj)
              if (jb + nj * 16 + lr > qrow) s_acc[mi][nj][r] = -1e30f;
          }
      }

      // ---- row max + reduce ----
      float pm[2][4];
#pragma unroll
      for (int mi = 0; mi < 2; ++mi)
#pragma unroll
        for (int r = 0; r < 4; ++r) {
          float mx = fmaxf(s_acc[mi][0][r], s_acc[mi][1][r]);
          mx = fmaxf(mx, __shfl_xor(mx, 1));
          mx = fmaxf(mx, __shfl_xor(mx, 2));
          mx = fmaxf(mx, __shfl_xor(mx, 4));
          mx = fmaxf(mx, __shfl_xor(mx, 8));
          pm[mi][r] = mx;
        }

      // ---- T13 defer-max: skip rescale if no row grew past m+8 ----
      bool ok = true;
#pragma unroll
      for (int mi = 0; mi < 2; ++mi)
#pragma unroll
        for (int r = 0; r < 4; ++r)
          ok = ok && (pm[mi][r] <= m_run[mi][r] + 8.0f);

      if (__all(ok)) {
#pragma unroll
        for (int mi = 0; mi < 2; ++mi)
#pragma unroll
          for (int r = 0; r < 4; ++r) {
            int prow = mi * 16 + lq * 4 + r;
            float rs = 0.0f;
#pragma unroll
            for (int nj = 0; nj < 2; ++nj) {
              float p = exp2f(s_acc[mi][nj][r] - m_run[mi][r]);
              rs += p;
              *(u16*)(PsB + prow * 72 + (nj * 16 + lr) * 2) = f2bf(p);
            }
            l_run[mi][r] += rs;
          }
      } else {
#pragma unroll
        for (int mi = 0; mi < 2; ++mi)
#pragma unroll
          for (int r = 0; r < 4; ++r) {
            float mnew = fmaxf(m_run[mi][r], pm[mi][r]);
            float sf = exp2f(m_run[mi][r] - mnew);
            m_run[mi][r] = mnew;
            int prow = mi * 16 + lq * 4 + r;
            float rs = 0.0f;
#pragma unroll
            for (int nj = 0; nj < 2; ++nj) {
              float p = exp2f(s_acc[mi][nj][r] - mnew);
              rs += p;
              *(u16*)(PsB + prow * 72 + (nj * 16 + lr) * 2) = f2bf(p);
            }
            l_run[mi][r] = l_run[mi][r] * sf + rs;
#pragma unroll
            for (int nd = 0; nd < 8; ++nd) acc_o[mi][nd][r] *= sf;
          }
      }

      // ---- O += P V  (32 x 128, K=32) ----
#pragma unroll
      for (int mi = 0; mi < 2; ++mi) {
        bf16x8 pa = *(const bf16x8*)(PsB + (mi * 16 + lr) * 72 + lq * 16);
#pragma unroll
        for (int nd = 0; nd < 8; ++nd) {
          int vrow = nd * 16 + lr;
          int key = (vrow & 3) ^ ((vrow >> 2) & 3);
          bf16x8 vb = *(const bf16x8*)(VsB + vrow * 64 + ((lq ^ key) << 4));
          acc_o[mi][nd] = __builtin_amdgcn_mfma_f32_16x16x32_bf16(
              pa, vb, acc_o[mi][nd], 0, 0, 0);
        }
      }
    }
    __builtin_amdgcn_sched_barrier(0);
    __builtin_amdgcn_s_barrier();
  }

  // epilogue: final l reduction + store
#pragma unroll
  for (int mi = 0; mi < 2; ++mi)
#pragma unroll
    for (int r = 0; r < 4; ++r) {
      float l = l_run[mi][r];
      l += __shfl_xor(l, 1);
      l += __shfl_xor(l, 2);
      l += __shfl_xor(l, 4);
      l += __shfl_xor(l, 8);
      float rl = 1.0f / l;
      int qrow = wrow0 + mi * 16 + lq * 4 + r;
#pragma unroll
      for (int nd = 0; nd < 8; ++nd)
        attn[(size_t)qrow * HID + h * HD + nd * 16 + lr] = f2bf(acc_o[mi][nd][r] * rl);
    }
}

extern "C" void kernel_launch(void* const* d_in, const int* in_sizes, int n_in,
                              void* d_out, int out_size, void* d_ws, size_t ws_size,
                              hipStream_t stream) {
  const float* hidden    = (const float*)d_in[0];
  const int*   positions = (const int*)d_in[1];
  const float* w_qkv     = (const float*)d_in[2];
  const float* w_o       = (const float*)d_in[3];
  float* out = (float*)d_out;

  char* p = (char*)d_ws;
  u16* hs_b   = (u16*)p;  p += (size_t)T_SEQ * HID * 2;
  u16* wqkvT  = (u16*)p;  p += (size_t)QKVN * HID * 2;
  u16* woT    = (u16*)p;  p += (size_t)HID * HID * 2;
  float* qkvf = (float*)p; p += (size_t)T_SEQ * QKVN * 4;
  u16* Qh     = (u16*)p;  p += (size_t)T_SEQ * HID * 2;
  u16* Kh     = (u16*)p;  p += (size_t)T_SEQ * HID * 2;
  u16* Vt     = (u16*)p;  p += (size_t)T_SEQ * HID * 2;
  u16* attn_b = (u16*)p;  p += (size_t)T_SEQ * HID * 2;

  cast_f32_bf16<<<(T_SEQ * HID / 4 + 255) / 256, 256, 0, stream>>>(hidden, hs_b, T_SEQ * HID);
  transpose_cast<<<dim3(QKVN / 64, HID / 64), 256, 0, stream>>>(w_qkv, wqkvT, HID, QKVN);
  transpose_cast<<<dim3(HID / 64, HID / 64), 256, 0, stream>>>(w_o, woT, HID, HID);
  gemm_bf16_bt<<<dim3(QKVN / 128, T_SEQ / 128), 256, 0, stream>>>(hs_b, wqkvT, qkvf,
                                                                  T_SEQ, QKVN, HID);
  rope_reorg<<<(T_SEQ * NH * 64 + 255) / 256, 256, 0, stream>>>(qkvf, positions, Qh, Kh);
  vtrans<<<dim3(T_SEQ / 64, NH), 256, 0, stream>>>(qkvf, Vt);
  attn_fwd<<<512, 256, 0, stream>>>(Qh, Kh, Vt, attn_b);
  gemm_bf16_bt<<<dim3(HID / 128, T_SEQ / 128), 256, 0, stream>>>(attn_b, woT, out,
                                                                 T_SEQ, HID, HID);
}

// Round 7
// 747.381 us; speedup vs baseline: 1.0234x; 1.0234x over previous
//
#include <hip/hip_runtime.h>
#include <hip/hip_bf16.h>
#include <cstdint>
#include <cstddef>

#define T_SEQ 4096
#define HID   2048
#define NH    16
#define HD    128
#define QKVN  6144
#define KVB   32

typedef unsigned short u16;
typedef __bf16 bf16x8 __attribute__((ext_vector_type(8)));
typedef float  f32x4  __attribute__((ext_vector_type(4)));

typedef const __attribute__((address_space(1))) void* gas_ptr;
typedef __attribute__((address_space(3))) void* las_ptr;

__device__ __forceinline__ void async16(const void* g, void* l) {
  __builtin_amdgcn_global_load_lds((gas_ptr)g, (las_ptr)l, 16, 0, 0);
}

__device__ __forceinline__ u16 f2bf(float f) {
  unsigned int u = __float_as_uint(f);
  u += 0x7fffu + ((u >> 16) & 1u);
  return (u16)(u >> 16);
}

__device__ __forceinline__ float bf2f(u16 x) {
  return __uint_as_float((unsigned)x << 16);
}

// ---------------- elementwise cast f32 -> bf16 ----------------
__global__ void cast_f32_bf16(const float* __restrict__ in, u16* __restrict__ out, int n) {
  int i = (blockIdx.x * blockDim.x + threadIdx.x) * 4;
  if (i >= n) return;
  float4 v = *(const float4*)&in[i];
  uint2 o;
  o.x = (unsigned)f2bf(v.x) | ((unsigned)f2bf(v.y) << 16);
  o.y = (unsigned)f2bf(v.z) | ((unsigned)f2bf(v.w) << 16);
  *(uint2*)&out[i] = o;
}

// ---------------- transpose + cast: f32 [R][C] -> bf16 [C][R] ----------------
__global__ void transpose_cast(const float* __restrict__ in, u16* __restrict__ out,
                               int R, int C) {
  __shared__ float tile[64][65];
  int c0 = blockIdx.x * 64, r0 = blockIdx.y * 64;
  int tid = threadIdx.x;
#pragma unroll
  for (int i = 0; i < 16; ++i) {
    int e = i * 256 + tid;
    int rr = e >> 6, cc = e & 63;
    tile[rr][cc] = in[(size_t)(r0 + rr) * C + c0 + cc];
  }
  __syncthreads();
#pragma unroll
  for (int i = 0; i < 16; ++i) {
    int e = i * 256 + tid;
    int oc = e >> 6, orr = e & 63;
    out[(size_t)(c0 + oc) * R + r0 + orr] = f2bf(tile[orr][oc]);
  }
}

// ---------------- GEMM: C[M][N] = A[M][K] * BT[N][K]^T  (bf16 in) ----------------
// 128x128 tile, BK=32, plain dbuf (__syncthreads; end-of-iter drain overlaps
// stage(t+1) with compute(t)). Key-swizzled LDS: 2 lanes/bank (free).
// OUT = u16 (bf16 store) or float.
template <typename OUT>
__global__ __launch_bounds__(256)
void gemm_bf16_bt(const u16* __restrict__ A, const u16* __restrict__ BT,
                  OUT* __restrict__ C, int M, int N, int K) {
  __shared__ u16 As[2][128 * 32];
  __shared__ u16 Bs[2][128 * 32];
  int tid = threadIdx.x;
  int row0 = blockIdx.y * 128, col0 = blockIdx.x * 128;
  int wv = tid >> 6, lane = tid & 63, lr = lane & 15, lq = lane >> 4;
  int wm = (wv >> 1) * 64, wn = (wv & 1) * 64;
  f32x4 acc[4][4] = {};

  auto stage = [&](int buf, int ks) {
#pragma unroll
    for (int k = 0; k < 2; ++k) {
      int c = k * 256 + tid;            // 512 chunks/matrix; dest lane-linear
      int row = c >> 2, col = c & 3;
      int key = (row & 3) ^ ((row >> 2) & 3);
      async16(&A[(size_t)(row0 + row) * K + ks + (col ^ key) * 8], &As[buf][c * 8]);
      async16(&BT[(size_t)(col0 + row) * K + ks + (col ^ key) * 8], &Bs[buf][c * 8]);
    }
  };

  stage(0, 0);
  __syncthreads();
  int nk = K >> 5;
  for (int t = 0; t < nk; ++t) {
    int cur = t & 1;
    if (t + 1 < nk) stage(cur ^ 1, (t + 1) * 32);

    const char* AsB = (const char*)&As[cur][0];
    const char* BsB = (const char*)&Bs[cur][0];
    bf16x8 a[4], b[4];
#pragma unroll
    for (int mi = 0; mi < 4; ++mi) {
      int row = wm + mi * 16 + lr;
      int key = (row & 3) ^ ((row >> 2) & 3);
      a[mi] = *(const bf16x8*)(AsB + row * 64 + ((lq ^ key) << 4));
    }
#pragma unroll
    for (int ni = 0; ni < 4; ++ni) {
      int row = wn + ni * 16 + lr;
      int key = (row & 3) ^ ((row >> 2) & 3);
      b[ni] = *(const bf16x8*)(BsB + row * 64 + ((lq ^ key) << 4));
    }
#pragma unroll
    for (int mi = 0; mi < 4; ++mi)
#pragma unroll
      for (int ni = 0; ni < 4; ++ni)
        acc[mi][ni] = __builtin_amdgcn_mfma_f32_16x16x32_bf16(a[mi], b[ni], acc[mi][ni], 0, 0, 0);
    __syncthreads();
  }

#pragma unroll
  for (int mi = 0; mi < 4; ++mi)
#pragma unroll
    for (int ni = 0; ni < 4; ++ni)
#pragma unroll
      for (int r = 0; r < 4; ++r) {
        float v = acc[mi][ni][r];
        size_t idx = (size_t)(row0 + wm + mi * 16 + lq * 4 + r) * N + col0 + wn + ni * 16 + lr;
        if constexpr (sizeof(OUT) == 2) C[idx] = (OUT)f2bf(v);
        else                            C[idx] = (OUT)v;
      }
}

// ---------------- RoPE + head-major reorg for Q,K (bf16 qkv input) ----------------
// Q pre-scaled by (1/sqrt(HD)) * log2(e) so softmax uses exp2 directly.
#define SCL2 0.12753224f

__global__ void rope_reorg(const u16* __restrict__ qkv, const int* __restrict__ pos,
                           u16* __restrict__ Qh, u16* __restrict__ Kh) {
  int idx = blockIdx.x * 256 + threadIdx.x;
  if (idx >= T_SEQ * NH * 64) return;
  int d = idx & 63;
  int h = (idx >> 6) & (NH - 1);
  int t = idx >> 10;
  float p = (float)pos[t];
  float inv = exp2f((float)d * -0.20762050594046932f);
  float f = p * inv;
  float s, c;
  __sincosf(f, &s, &c);

  size_t ib = (size_t)t * QKVN + h * HD + d;
  float q1 = bf2f(qkv[ib]), q2 = bf2f(qkv[ib + 64]);
  float k1 = bf2f(qkv[ib + HID]), k2 = bf2f(qkv[ib + HID + 64]);
  size_t ob = ((size_t)h * T_SEQ + t) * HD + d;
  Qh[ob]      = f2bf((q1 * c - q2 * s) * SCL2);
  Qh[ob + 64] = f2bf((q2 * c + q1 * s) * SCL2);
  Kh[ob]      = f2bf(k1 * c - k2 * s);
  Kh[ob + 64] = f2bf(k2 * c + k1 * s);
}

// ---------------- V transpose: qkv v-part bf16 -> Vt bf16 [NH][HD][T] -------------
__global__ void vtrans(const u16* __restrict__ qkv, u16* __restrict__ Vt) {
  __shared__ u16 tile[64][136];   // +8 u16 pad
  int t0 = blockIdx.x * 64;
  int h = blockIdx.y;
  int tid = threadIdx.x;
#pragma unroll
  for (int i = 0; i < 32; ++i) {
    int e = i * 256 + tid;
    int tt = e >> 7, d = e & 127;
    tile[tt][d] = qkv[(size_t)(t0 + tt) * QKVN + 2 * HID + h * HD + d];
  }
  __syncthreads();
#pragma unroll
  for (int i = 0; i < 32; ++i) {
    int e = i * 256 + tid;
    int d = e >> 6, tt = e & 63;
    Vt[((size_t)h * HD + d) * T_SEQ + t0 + tt] = tile[tt][d];
  }
}

// ---------------- causal flash attention v7 (R4 structure + fixes) ---------------
// 4 waves/block, Q-tile 128 (32 rows/wave), KVBLK=32, plain-dbuf __syncthreads
// pipeline (proven R4). K XOR-8 swizzle; V key swizzle (2-way = free); P 72B
// padded rows. Scale folded into Q, deferred l, wave-uniform mask, defer-max.
__global__ __launch_bounds__(256)
void attn_fwd(const u16* __restrict__ Qh, const u16* __restrict__ Kh,
              const u16* __restrict__ Vt, u16* __restrict__ attn) {
  __shared__ u16 Ks[2][32 * 128];   // [kv][d] 256B rows, XOR-8 swizzle
  __shared__ u16 Vs[2][128 * 32];   // [d][kv] 64B rows, key swizzle
  __shared__ u16 Ps[4][32 * 36];    // per-wave [q][kv], 72B padded rows

  int tid = threadIdx.x;
  int wv = tid >> 6, lane = tid & 63, lr = lane & 15, lq = lane >> 4;
  // balanced decode: CU-paired blocks get bq and 31-bq
  int id = blockIdx.x;
  int h = id >> 5;
  int bq = (id < 256) ? (id & 31) : 31 - (id & 31);
  int q0 = bq * 128, wrow0 = q0 + wv * 32;
  char* PsB = (char*)&Ps[wv][0];

  // Q fragments (pre-scaled): rows wrow0 + mi*16 + lr, k = kd*32 + lq*8
  bf16x8 qf[2][4];
#pragma unroll
  for (int mi = 0; mi < 2; ++mi)
#pragma unroll
    for (int kd = 0; kd < 4; ++kd)
      qf[mi][kd] = *(const bf16x8*)
          &Qh[((size_t)h * T_SEQ + wrow0 + mi * 16 + lr) * HD + kd * 32 + lq * 8];

  f32x4 acc_o[2][8] = {};
  float m_run[2][4], l_run[2][4];
#pragma unroll
  for (int mi = 0; mi < 2; ++mi)
#pragma unroll
    for (int r = 0; r < 4; ++r) { m_run[mi][r] = -1e30f; l_run[mi][r] = 0.0f; }

  auto stage = [&](int buf, int jb) {
#pragma unroll
    for (int k = 0; k < 2; ++k) {      // K tile: 512 chunks, 16/row, src pre-swz
      int c = k * 256 + tid;
      int row = c >> 4;
      int sc = (c ^ (row & 7)) & 15;
      async16(&Kh[((size_t)h * T_SEQ + jb + row) * HD + sc * 8], &Ks[buf][c * 8]);
    }
#pragma unroll
    for (int k = 0; k < 2; ++k) {      // V tile: 512 chunks, 4/row, key-swz
      int c = k * 256 + tid;
      int row = c >> 2, col = c & 3;
      int key = (row & 3) ^ ((row >> 2) & 3);
      async16(&Vt[((size_t)h * HD + row) * T_SEQ + jb + (col ^ key) * 8],
              &Vs[buf][c * 8]);
    }
  };

  int nt = bq * 4 + 4;
  stage(0, 0);
  __syncthreads();

  for (int j = 0; j < nt; ++j) {
    int cur = j & 1;
    int jb = j * KVB;
    if (j + 1 < nt) stage(cur ^ 1, jb + KVB);

    if (jb <= wrow0 + 31) {
      const char* KsB = (const char*)&Ks[cur][0];
      const char* VsB = (const char*)&Vs[cur][0];

      // ---- S = Q K^T  (32 x 32) ----
      f32x4 s_acc[2][2] = {};
#pragma unroll
      for (int kd = 0; kd < 4; ++kd) {
#pragma unroll
        for (int nj = 0; nj < 2; ++nj) {
          int row = nj * 16 + lr;
          int byt = (row << 8) + kd * 64 + lq * 16;
          bf16x8 kf = *(const bf16x8*)(KsB + (byt ^ ((row & 7) << 4)));
#pragma unroll
          for (int mi = 0; mi < 2; ++mi)
            s_acc[mi][nj] = __builtin_amdgcn_mfma_f32_16x16x32_bf16(
                qf[mi][kd], kf, s_acc[mi][nj], 0, 0, 0);
        }
      }

      // ---- causal mask (wave-uniform branch) ----
      if (jb + KVB - 1 > wrow0) {
#pragma unroll
        for (int mi = 0; mi < 2; ++mi)
#pragma unroll
          for (int r = 0; r < 4; ++r) {
            int qrow = wrow0 + mi * 16 + lq * 4 + r;
#pragma unroll
            for (int nj = 0; nj < 2; ++nj)
              if (jb + nj * 16 + lr > qrow) s_acc[mi][nj][r] = -1e30f;
          }
      }

      // ---- row max + reduce ----
      float pm[2][4];
#pragma unroll
      for (int mi = 0; mi < 2; ++mi)
#pragma unroll
        for (int r = 0; r < 4; ++r) {
          float mx = fmaxf(s_acc[mi][0][r], s_acc[mi][1][r]);
          mx = fmaxf(mx, __shfl_xor(mx, 1));
          mx = fmaxf(mx, __shfl_xor(mx, 2));
          mx = fmaxf(mx, __shfl_xor(mx, 4));
          mx = fmaxf(mx, __shfl_xor(mx, 8));
          pm[mi][r] = mx;
        }

      // ---- T13 defer-max: skip rescale if no row grew past m+8 ----
      bool ok = true;
#pragma unroll
      for (int mi = 0; mi < 2; ++mi)
#pragma unroll
        for (int r = 0; r < 4; ++r)
          ok = ok && (pm[mi][r] <= m_run[mi][r] + 8.0f);

      if (__all(ok)) {
#pragma unroll
        for (int mi = 0; mi < 2; ++mi)
#pragma unroll
          for (int r = 0; r < 4; ++r) {
            int prow = mi * 16 + lq * 4 + r;
            float rs = 0.0f;
#pragma unroll
            for (int nj = 0; nj < 2; ++nj) {
              float p = exp2f(s_acc[mi][nj][r] - m_run[mi][r]);
              rs += p;
              *(u16*)(PsB + prow * 72 + (nj * 16 + lr) * 2) = f2bf(p);
            }
            l_run[mi][r] += rs;
          }
      } else {
#pragma unroll
        for (int mi = 0; mi < 2; ++mi)
#pragma unroll
          for (int r = 0; r < 4; ++r) {
            float mnew = fmaxf(m_run[mi][r], pm[mi][r]);
            float sf = exp2f(m_run[mi][r] - mnew);
            m_run[mi][r] = mnew;
            int prow = mi * 16 + lq * 4 + r;
            float rs = 0.0f;
#pragma unroll
            for (int nj = 0; nj < 2; ++nj) {
              float p = exp2f(s_acc[mi][nj][r] - mnew);
              rs += p;
              *(u16*)(PsB + prow * 72 + (nj * 16 + lr) * 2) = f2bf(p);
            }
            l_run[mi][r] = l_run[mi][r] * sf + rs;
#pragma unroll
            for (int nd = 0; nd < 8; ++nd) acc_o[mi][nd][r] *= sf;
          }
      }

      // ---- O += P V  (32 x 128, K=32) ----
#pragma unroll
      for (int mi = 0; mi < 2; ++mi) {
        bf16x8 pa = *(const bf16x8*)(PsB + (mi * 16 + lr) * 72 + lq * 16);
#pragma unroll
        for (int nd = 0; nd < 8; ++nd) {
          int vrow = nd * 16 + lr;
          int key = (vrow & 3) ^ ((vrow >> 2) & 3);
          bf16x8 vb = *(const bf16x8*)(VsB + vrow * 64 + ((lq ^ key) << 4));
          acc_o[mi][nd] = __builtin_amdgcn_mfma_f32_16x16x32_bf16(
              pa, vb, acc_o[mi][nd], 0, 0, 0);
        }
      }
    }
    __syncthreads();
  }

  // epilogue: final l reduction + store
#pragma unroll
  for (int mi = 0; mi < 2; ++mi)
#pragma unroll
    for (int r = 0; r < 4; ++r) {
      float l = l_run[mi][r];
      l += __shfl_xor(l, 1);
      l += __shfl_xor(l, 2);
      l += __shfl_xor(l, 4);
      l += __shfl_xor(l, 8);
      float rl = 1.0f / l;
      int qrow = wrow0 + mi * 16 + lq * 4 + r;
#pragma unroll
      for (int nd = 0; nd < 8; ++nd)
        attn[(size_t)qrow * HID + h * HD + nd * 16 + lr] = f2bf(acc_o[mi][nd][r] * rl);
    }
}

extern "C" void kernel_launch(void* const* d_in, const int* in_sizes, int n_in,
                              void* d_out, int out_size, void* d_ws, size_t ws_size,
                              hipStream_t stream) {
  const float* hidden    = (const float*)d_in[0];
  const int*   positions = (const int*)d_in[1];
  const float* w_qkv     = (const float*)d_in[2];
  const float* w_o       = (const float*)d_in[3];
  float* out = (float*)d_out;

  char* p = (char*)d_ws;
  u16* hs_b   = (u16*)p;  p += (size_t)T_SEQ * HID * 2;
  u16* wqkvT  = (u16*)p;  p += (size_t)QKVN * HID * 2;
  u16* woT    = (u16*)p;  p += (size_t)HID * HID * 2;
  u16* qkvb   = (u16*)p;  p += (size_t)T_SEQ * QKVN * 2;
  u16* Qh     = (u16*)p;  p += (size_t)T_SEQ * HID * 2;
  u16* Kh     = (u16*)p;  p += (size_t)T_SEQ * HID * 2;
  u16* Vt     = (u16*)p;  p += (size_t)T_SEQ * HID * 2;
  u16* attn_b = (u16*)p;  p += (size_t)T_SEQ * HID * 2;

  cast_f32_bf16<<<(T_SEQ * HID / 4 + 255) / 256, 256, 0, stream>>>(hidden, hs_b, T_SEQ * HID);
  transpose_cast<<<dim3(QKVN / 64, HID / 64), 256, 0, stream>>>(w_qkv, wqkvT, HID, QKVN);
  transpose_cast<<<dim3(HID / 64, HID / 64), 256, 0, stream>>>(w_o, woT, HID, HID);
  gemm_bf16_bt<u16><<<dim3(QKVN / 128, T_SEQ / 128), 256, 0, stream>>>(hs_b, wqkvT, qkvb,
                                                                       T_SEQ, QKVN, HID);
  rope_reorg<<<(T_SEQ * NH * 64 + 255) / 256, 256, 0, stream>>>(qkvb, positions, Qh, Kh);
  vtrans<<<dim3(T_SEQ / 64, NH), 256, 0, stream>>>(qkvb, Vt);
  attn_fwd<<<512, 256, 0, stream>>>(Qh, Kh, Vt, attn_b);
  gemm_bf16_bt<float><<<dim3(HID / 128, T_SEQ / 128), 256, 0, stream>>>(attn_b, woT, out,
                                                                        T_SEQ, HID, HID);
}

// Round 8
// 705.433 us; speedup vs baseline: 1.0843x; 1.0595x over previous
//
#include <hip/hip_runtime.h>
#include <hip/hip_bf16.h>
#include <cstdint>
#include <cstddef>

#define T_SEQ 4096
#define HID   2048
#define NH    16
#define HD    128
#define QKVN  6144
#define KVB   64

typedef unsigned short u16;
typedef __bf16 bf16x8 __attribute__((ext_vector_type(8)));
typedef float  f32x4  __attribute__((ext_vector_type(4)));

typedef const __attribute__((address_space(1))) void* gas_ptr;
typedef __attribute__((address_space(3))) void* las_ptr;

__device__ __forceinline__ void async16(const void* g, void* l) {
  __builtin_amdgcn_global_load_lds((gas_ptr)g, (las_ptr)l, 16, 0, 0);
}

__device__ __forceinline__ u16 f2bf(float f) {
  unsigned int u = __float_as_uint(f);
  u += 0x7fffu + ((u >> 16) & 1u);
  return (u16)(u >> 16);
}

__device__ __forceinline__ float bf2f(u16 x) {
  return __uint_as_float((unsigned)x << 16);
}

// ---------------- elementwise cast f32 -> bf16 ----------------
__global__ void cast_f32_bf16(const float* __restrict__ in, u16* __restrict__ out, int n) {
  int i = (blockIdx.x * blockDim.x + threadIdx.x) * 4;
  if (i >= n) return;
  float4 v = *(const float4*)&in[i];
  uint2 o;
  o.x = (unsigned)f2bf(v.x) | ((unsigned)f2bf(v.y) << 16);
  o.y = (unsigned)f2bf(v.z) | ((unsigned)f2bf(v.w) << 16);
  *(uint2*)&out[i] = o;
}

// ---------------- transpose + cast: f32 [R][C] -> bf16 [C][R] ----------------
__global__ void transpose_cast(const float* __restrict__ in, u16* __restrict__ out,
                               int R, int C) {
  __shared__ float tile[64][65];
  int c0 = blockIdx.x * 64, r0 = blockIdx.y * 64;
  int tid = threadIdx.x;
#pragma unroll
  for (int i = 0; i < 16; ++i) {
    int e = i * 256 + tid;
    int rr = e >> 6, cc = e & 63;
    tile[rr][cc] = in[(size_t)(r0 + rr) * C + c0 + cc];
  }
  __syncthreads();
#pragma unroll
  for (int i = 0; i < 16; ++i) {
    int e = i * 256 + tid;
    int oc = e >> 6, orr = e & 63;
    out[(size_t)(c0 + oc) * R + r0 + orr] = f2bf(tile[orr][oc]);
  }
}

// ---------------- GEMM: C[M][N] = A[M][K] * BT[N][K]^T  (bf16 in) ----------------
// 128x128 tile, BK=32, plain dbuf; key-swizzled LDS (8-lane-group conflict-free).
template <typename OUT>
__global__ __launch_bounds__(256)
void gemm_bf16_bt(const u16* __restrict__ A, const u16* __restrict__ BT,
                  OUT* __restrict__ C, int M, int N, int K) {
  __shared__ u16 As[2][128 * 32];
  __shared__ u16 Bs[2][128 * 32];
  int tid = threadIdx.x;
  int row0 = blockIdx.y * 128, col0 = blockIdx.x * 128;
  int wv = tid >> 6, lane = tid & 63, lr = lane & 15, lq = lane >> 4;
  int wm = (wv >> 1) * 64, wn = (wv & 1) * 64;
  f32x4 acc[4][4] = {};

  auto stage = [&](int buf, int ks) {
#pragma unroll
    for (int k = 0; k < 2; ++k) {
      int c = k * 256 + tid;            // 512 chunks/matrix; dest lane-linear
      int row = c >> 2, col = c & 3;
      int key = (row & 3) ^ ((row >> 2) & 3);
      async16(&A[(size_t)(row0 + row) * K + ks + (col ^ key) * 8], &As[buf][c * 8]);
      async16(&BT[(size_t)(col0 + row) * K + ks + (col ^ key) * 8], &Bs[buf][c * 8]);
    }
  };

  stage(0, 0);
  __syncthreads();
  int nk = K >> 5;
  for (int t = 0; t < nk; ++t) {
    int cur = t & 1;
    if (t + 1 < nk) stage(cur ^ 1, (t + 1) * 32);

    const char* AsB = (const char*)&As[cur][0];
    const char* BsB = (const char*)&Bs[cur][0];
    bf16x8 a[4], b[4];
#pragma unroll
    for (int mi = 0; mi < 4; ++mi) {
      int row = wm + mi * 16 + lr;
      int key = (row & 3) ^ ((row >> 2) & 3);
      a[mi] = *(const bf16x8*)(AsB + row * 64 + ((lq ^ key) << 4));
    }
#pragma unroll
    for (int ni = 0; ni < 4; ++ni) {
      int row = wn + ni * 16 + lr;
      int key = (row & 3) ^ ((row >> 2) & 3);
      b[ni] = *(const bf16x8*)(BsB + row * 64 + ((lq ^ key) << 4));
    }
#pragma unroll
    for (int mi = 0; mi < 4; ++mi)
#pragma unroll
      for (int ni = 0; ni < 4; ++ni)
        acc[mi][ni] = __builtin_amdgcn_mfma_f32_16x16x32_bf16(a[mi], b[ni], acc[mi][ni], 0, 0, 0);
    __syncthreads();
  }

#pragma unroll
  for (int mi = 0; mi < 4; ++mi)
#pragma unroll
    for (int ni = 0; ni < 4; ++ni)
#pragma unroll
      for (int r = 0; r < 4; ++r) {
        float v = acc[mi][ni][r];
        size_t idx = (size_t)(row0 + wm + mi * 16 + lq * 4 + r) * N + col0 + wn + ni * 16 + lr;
        if constexpr (sizeof(OUT) == 2) C[idx] = (OUT)f2bf(v);
        else                            C[idx] = (OUT)v;
      }
}

// ---------------- RoPE + head-major reorg for Q,K (bf16 qkv input) ----------------
// Q pre-scaled by (1/sqrt(HD)) * log2(e) so softmax uses exp2 directly.
#define SCL2 0.12753224f

__global__ void rope_reorg(const u16* __restrict__ qkv, const int* __restrict__ pos,
                           u16* __restrict__ Qh, u16* __restrict__ Kh) {
  int idx = blockIdx.x * 256 + threadIdx.x;
  if (idx >= T_SEQ * NH * 64) return;
  int d = idx & 63;
  int h = (idx >> 6) & (NH - 1);
  int t = idx >> 10;
  float p = (float)pos[t];
  float inv = exp2f((float)d * -0.20762050594046932f);
  float f = p * inv;
  float s, c;
  __sincosf(f, &s, &c);

  size_t ib = (size_t)t * QKVN + h * HD + d;
  float q1 = bf2f(qkv[ib]), q2 = bf2f(qkv[ib + 64]);
  float k1 = bf2f(qkv[ib + HID]), k2 = bf2f(qkv[ib + HID + 64]);
  size_t ob = ((size_t)h * T_SEQ + t) * HD + d;
  Qh[ob]      = f2bf((q1 * c - q2 * s) * SCL2);
  Qh[ob + 64] = f2bf((q2 * c + q1 * s) * SCL2);
  Kh[ob]      = f2bf(k1 * c - k2 * s);
  Kh[ob + 64] = f2bf(k2 * c + k1 * s);
}

// ---------------- V transpose: qkv v-part bf16 -> Vt bf16 [NH][HD][T] -------------
__global__ void vtrans(const u16* __restrict__ qkv, u16* __restrict__ Vt) {
  __shared__ u16 tile[64][136];   // +8 u16 pad
  int t0 = blockIdx.x * 64;
  int h = blockIdx.y;
  int tid = threadIdx.x;
#pragma unroll
  for (int i = 0; i < 32; ++i) {
    int e = i * 256 + tid;
    int tt = e >> 7, d = e & 127;
    tile[tt][d] = qkv[(size_t)(t0 + tt) * QKVN + 2 * HID + h * HD + d];
  }
  __syncthreads();
#pragma unroll
  for (int i = 0; i < 32; ++i) {
    int e = i * 256 + tid;
    int d = e >> 6, tt = e & 63;
    Vt[((size_t)h * HD + d) * T_SEQ + t0 + tt] = tile[tt][d];
  }
}

// ---------------- causal flash attention v8: R4 structure, KVB=64 ----------------
// 4 waves/block, Q-tile 128 (32 rows/wave), KVBLK=64 (halves iteration count ->
// halves per-tile barrier-drain overhead), plain-dbuf __syncthreads pipeline.
// All LDS tiles XOR-8 swizzled (128/256B rows -> conflict-free per 8-lane group).
// Softmax identical to R4 (always-rescale, inline l shfl-reduce).
__global__ __launch_bounds__(256)
void attn_fwd(const u16* __restrict__ Qh, const u16* __restrict__ Kh,
              const u16* __restrict__ Vt, u16* __restrict__ attn) {
  __shared__ u16 Ks[2][KVB * 128];  // [kv][d] 256B rows, XOR-8 swizzle (16KB ea)
  __shared__ u16 Vs[2][128 * KVB];  // [d][kv] 128B rows, XOR-8 swizzle (16KB ea)
  __shared__ u16 Ps[4][32 * KVB];   // per-wave [q][kv] 128B rows, XOR-8 (4KB ea)

  int tid = threadIdx.x;
  int wv = tid >> 6, lane = tid & 63, lr = lane & 15, lq = lane >> 4;
  // balanced decode: CU-paired blocks get bq and 31-bq
  int id = blockIdx.x;
  int h = id >> 5;
  int bq = (id < 256) ? (id & 31) : 31 - (id & 31);
  int q0 = bq * 128, wrow0 = q0 + wv * 32;
  char* PsB = (char*)&Ps[wv][0];

  // Q fragments (pre-scaled): rows wrow0 + mi*16 + lr, k = kd*32 + lq*8
  bf16x8 qf[2][4];
#pragma unroll
  for (int mi = 0; mi < 2; ++mi)
#pragma unroll
    for (int kd = 0; kd < 4; ++kd)
      qf[mi][kd] = *(const bf16x8*)
          &Qh[((size_t)h * T_SEQ + wrow0 + mi * 16 + lr) * HD + kd * 32 + lq * 8];

  f32x4 acc_o[2][8] = {};
  float m_run[2][4], l_run[2][4];
#pragma unroll
  for (int mi = 0; mi < 2; ++mi)
#pragma unroll
    for (int r = 0; r < 4; ++r) { m_run[mi][r] = -1e30f; l_run[mi][r] = 0.0f; }

  auto stage = [&](int buf, int jb) {
#pragma unroll
    for (int k = 0; k < 4; ++k) {      // K tile: 1024 chunks, 16/row, src pre-swz
      int c = k * 256 + tid;
      int row = c >> 4;
      int sc = (c ^ (row & 7)) & 15;
      async16(&Kh[((size_t)h * T_SEQ + jb + row) * HD + sc * 8], &Ks[buf][c * 8]);
    }
#pragma unroll
    for (int k = 0; k < 4; ++k) {      // V tile: 1024 chunks, 8/row, src pre-swz
      int c = k * 256 + tid;
      int row = c >> 3;
      int sc = (c ^ (row & 7)) & 7;
      async16(&Vt[((size_t)h * HD + row) * T_SEQ + jb + sc * 8], &Vs[buf][c * 8]);
    }
  };

  int nt = bq * 2 + 2;
  stage(0, 0);
  __syncthreads();

  for (int j = 0; j < nt; ++j) {
    int cur = j & 1;
    int jb = j * KVB;
    if (j + 1 < nt) stage(cur ^ 1, jb + KVB);

    if (jb <= wrow0 + 31) {
      const char* KsB = (const char*)&Ks[cur][0];
      const char* VsB = (const char*)&Vs[cur][0];
      bool diag = (jb + KVB - 1 > wrow0);

      // ---- S = Q K^T  (32 x 64) ----
      f32x4 s_acc[2][4] = {};
#pragma unroll
      for (int kd = 0; kd < 4; ++kd) {
#pragma unroll
        for (int nj = 0; nj < 4; ++nj) {
          int row = nj * 16 + lr;
          int byt = (row << 8) + kd * 64 + lq * 16;
          bf16x8 kf = *(const bf16x8*)(KsB + (byt ^ ((row & 7) << 4)));
#pragma unroll
          for (int mi = 0; mi < 2; ++mi)
            s_acc[mi][nj] = __builtin_amdgcn_mfma_f32_16x16x32_bf16(
                qf[mi][kd], kf, s_acc[mi][nj], 0, 0, 0);
        }
      }

      // ---- online softmax (R4 pattern, nj=4) ----
#pragma unroll
      for (int mi = 0; mi < 2; ++mi) {
        float pm[4];
#pragma unroll
        for (int r = 0; r < 4; ++r) {
          int qrow = wrow0 + mi * 16 + lq * 4 + r;
          float mx = -1e30f;
#pragma unroll
          for (int nj = 0; nj < 4; ++nj) {
            float s = s_acc[mi][nj][r];
            if (diag && (jb + nj * 16 + lr > qrow)) s = -1e30f;
            s_acc[mi][nj][r] = s;
            mx = fmaxf(mx, s);
          }
          pm[r] = mx;
        }
#pragma unroll
        for (int r = 0; r < 4; ++r) {
          pm[r] = fmaxf(pm[r], __shfl_xor(pm[r], 1));
          pm[r] = fmaxf(pm[r], __shfl_xor(pm[r], 2));
          pm[r] = fmaxf(pm[r], __shfl_xor(pm[r], 4));
          pm[r] = fmaxf(pm[r], __shfl_xor(pm[r], 8));
        }
#pragma unroll
        for (int r = 0; r < 4; ++r) {
          float mnew = fmaxf(m_run[mi][r], pm[r]);
          float sf = exp2f(m_run[mi][r] - mnew);
          m_run[mi][r] = mnew;
          int prow = mi * 16 + lq * 4 + r;
          float rs = 0.0f;
#pragma unroll
          for (int nj = 0; nj < 4; ++nj) {
            float p = exp2f(s_acc[mi][nj][r] - mnew);
            rs += p;
            int byt = (prow << 7) + (nj * 16 + lr) * 2;
            *(u16*)(PsB + (byt ^ ((prow & 7) << 4))) = f2bf(p);
          }
          rs += __shfl_xor(rs, 1);
          rs += __shfl_xor(rs, 2);
          rs += __shfl_xor(rs, 4);
          rs += __shfl_xor(rs, 8);
          l_run[mi][r] = l_run[mi][r] * sf + rs;
          m_run[mi][r] = mnew;
#pragma unroll
          for (int nd = 0; nd < 8; ++nd) acc_o[mi][nd][r] *= sf;
        }
      }

      // ---- O += P V  (32 x 128, K=64) ----
#pragma unroll
      for (int kq = 0; kq < 2; ++kq) {
#pragma unroll
        for (int mi = 0; mi < 2; ++mi) {
          int prow = mi * 16 + lr;
          int pbyt = (prow << 7) + kq * 64 + lq * 16;
          bf16x8 pa = *(const bf16x8*)(PsB + (pbyt ^ ((prow & 7) << 4)));
#pragma unroll
          for (int nd = 0; nd < 8; ++nd) {
            int vrow = nd * 16 + lr;
            int vbyt = (vrow << 7) + kq * 64 + lq * 16;
            bf16x8 vb = *(const bf16x8*)(VsB + (vbyt ^ ((vrow & 7) << 4)));
            acc_o[mi][nd] = __builtin_amdgcn_mfma_f32_16x16x32_bf16(
                pa, vb, acc_o[mi][nd], 0, 0, 0);
          }
        }
      }
    }
    __syncthreads();
  }

  // epilogue
#pragma unroll
  for (int mi = 0; mi < 2; ++mi)
#pragma unroll
    for (int r = 0; r < 4; ++r) {
      float rl = 1.0f / l_run[mi][r];
      int qrow = wrow0 + mi * 16 + lq * 4 + r;
#pragma unroll
      for (int nd = 0; nd < 8; ++nd)
        attn[(size_t)qrow * HID + h * HD + nd * 16 + lr] = f2bf(acc_o[mi][nd][r] * rl);
    }
}

extern "C" void kernel_launch(void* const* d_in, const int* in_sizes, int n_in,
                              void* d_out, int out_size, void* d_ws, size_t ws_size,
                              hipStream_t stream) {
  const float* hidden    = (const float*)d_in[0];
  const int*   positions = (const int*)d_in[1];
  const float* w_qkv     = (const float*)d_in[2];
  const float* w_o       = (const float*)d_in[3];
  float* out = (float*)d_out;

  char* p = (char*)d_ws;
  u16* hs_b   = (u16*)p;  p += (size_t)T_SEQ * HID * 2;
  u16* wqkvT  = (u16*)p;  p += (size_t)QKVN * HID * 2;
  u16* woT    = (u16*)p;  p += (size_t)HID * HID * 2;
  u16* qkvb   = (u16*)p;  p += (size_t)T_SEQ * QKVN * 2;
  u16* Qh     = (u16*)p;  p += (size_t)T_SEQ * HID * 2;
  u16* Kh     = (u16*)p;  p += (size_t)T_SEQ * HID * 2;
  u16* Vt     = (u16*)p;  p += (size_t)T_SEQ * HID * 2;
  u16* attn_b = (u16*)p;  p += (size_t)T_SEQ * HID * 2;

  cast_f32_bf16<<<(T_SEQ * HID / 4 + 255) / 256, 256, 0, stream>>>(hidden, hs_b, T_SEQ * HID);
  transpose_cast<<<dim3(QKVN / 64, HID / 64), 256, 0, stream>>>(w_qkv, wqkvT, HID, QKVN);
  transpose_cast<<<dim3(HID / 64, HID / 64), 256, 0, stream>>>(w_o, woT, HID, HID);
  gemm_bf16_bt<u16><<<dim3(QKVN / 128, T_SEQ / 128), 256, 0, stream>>>(hs_b, wqkvT, qkvb,
                                                                       T_SEQ, QKVN, HID);
  rope_reorg<<<(T_SEQ * NH * 64 + 255) / 256, 256, 0, stream>>>(qkvb, positions, Qh, Kh);
  vtrans<<<dim3(T_SEQ / 64, NH), 256, 0, stream>>>(qkvb, Vt);
  attn_fwd<<<512, 256, 0, stream>>>(Qh, Kh, Vt, attn_b);
  gemm_bf16_bt<float><<<dim3(HID / 128, T_SEQ / 128), 256, 0, stream>>>(attn_b, woT, out,
                                                                        T_SEQ, HID, HID);
}

// Round 9
// 627.048 us; speedup vs baseline: 1.2198x; 1.1250x over previous
//
#include <hip/hip_runtime.h>
#include <hip/hip_bf16.h>
#include <cstdint>
#include <cstddef>

#define T_SEQ 4096
#define HID   2048
#define NH    16
#define HD    128
#define QKVN  6144
#define KVB   32

typedef unsigned short u16;
typedef unsigned int u32;
typedef __bf16 bf16x8 __attribute__((ext_vector_type(8)));
typedef float  f32x4  __attribute__((ext_vector_type(4)));

typedef const __attribute__((address_space(1))) void* gas_ptr;
typedef __attribute__((address_space(3))) void* las_ptr;

__device__ __forceinline__ void async16(const void* g, void* l) {
  __builtin_amdgcn_global_load_lds((gas_ptr)g, (las_ptr)l, 16, 0, 0);
}

__device__ __forceinline__ u16 f2bf(float f) {
  unsigned int u = __float_as_uint(f);
  u += 0x7fffu + ((u >> 16) & 1u);
  return (u16)(u >> 16);
}

__device__ __forceinline__ float bf2f(u16 x) {
  return __uint_as_float((unsigned)x << 16);
}

// ---------------- elementwise cast f32 -> bf16 ----------------
__global__ void cast_f32_bf16(const float* __restrict__ in, u16* __restrict__ out, int n) {
  int i = (blockIdx.x * blockDim.x + threadIdx.x) * 4;
  if (i >= n) return;
  float4 v = *(const float4*)&in[i];
  uint2 o;
  o.x = (unsigned)f2bf(v.x) | ((unsigned)f2bf(v.y) << 16);
  o.y = (unsigned)f2bf(v.z) | ((unsigned)f2bf(v.w) << 16);
  *(uint2*)&out[i] = o;
}

// ---------------- transpose + cast: f32 [R][C] -> bf16 [C][R] ----------------
__global__ void transpose_cast(const float* __restrict__ in, u16* __restrict__ out,
                               int R, int C) {
  __shared__ float tile[64][65];
  int c0 = blockIdx.x * 64, r0 = blockIdx.y * 64;
  int tid = threadIdx.x;
#pragma unroll
  for (int i = 0; i < 16; ++i) {
    int e = i * 256 + tid;
    int rr = e >> 6, cc = e & 63;
    tile[rr][cc] = in[(size_t)(r0 + rr) * C + c0 + cc];
  }
  __syncthreads();
#pragma unroll
  for (int i = 0; i < 16; ++i) {
    int e = i * 256 + tid;
    int oc = e >> 6, orr = e & 63;
    out[(size_t)(c0 + oc) * R + r0 + orr] = f2bf(tile[orr][oc]);
  }
}

// ---------------- GEMM: C[M][N] = A[M][K] * BT[N][K]^T  (bf16 in) ----------------
// 128x128 tile, BK=32, plain dbuf; key-swizzled LDS.
template <typename OUT>
__global__ __launch_bounds__(256)
void gemm_bf16_bt(const u16* __restrict__ A, const u16* __restrict__ BT,
                  OUT* __restrict__ C, int M, int N, int K) {
  __shared__ u16 As[2][128 * 32];
  __shared__ u16 Bs[2][128 * 32];
  int tid = threadIdx.x;
  int row0 = blockIdx.y * 128, col0 = blockIdx.x * 128;
  int wv = tid >> 6, lane = tid & 63, lr = lane & 15, lq = lane >> 4;
  int wm = (wv >> 1) * 64, wn = (wv & 1) * 64;
  f32x4 acc[4][4] = {};

  auto stage = [&](int buf, int ks) {
#pragma unroll
    for (int k = 0; k < 2; ++k) {
      int c = k * 256 + tid;            // 512 chunks/matrix; dest lane-linear
      int row = c >> 2, col = c & 3;
      int key = (row >> 1) & 3;
      async16(&A[(size_t)(row0 + row) * K + ks + (col ^ key) * 8], &As[buf][c * 8]);
      async16(&BT[(size_t)(col0 + row) * K + ks + (col ^ key) * 8], &Bs[buf][c * 8]);
    }
  };

  stage(0, 0);
  __syncthreads();
  int nk = K >> 5;
  for (int t = 0; t < nk; ++t) {
    int cur = t & 1;
    if (t + 1 < nk) stage(cur ^ 1, (t + 1) * 32);

    const char* AsB = (const char*)&As[cur][0];
    const char* BsB = (const char*)&Bs[cur][0];
    bf16x8 a[4], b[4];
#pragma unroll
    for (int mi = 0; mi < 4; ++mi) {
      int row = wm + mi * 16 + lr;
      a[mi] = *(const bf16x8*)(AsB + row * 64 + ((lq ^ ((row >> 1) & 3)) << 4));
    }
#pragma unroll
    for (int ni = 0; ni < 4; ++ni) {
      int row = wn + ni * 16 + lr;
      b[ni] = *(const bf16x8*)(BsB + row * 64 + ((lq ^ ((row >> 1) & 3)) << 4));
    }
#pragma unroll
    for (int mi = 0; mi < 4; ++mi)
#pragma unroll
      for (int ni = 0; ni < 4; ++ni)
        acc[mi][ni] = __builtin_amdgcn_mfma_f32_16x16x32_bf16(a[mi], b[ni], acc[mi][ni], 0, 0, 0);
    __syncthreads();
  }

#pragma unroll
  for (int mi = 0; mi < 4; ++mi)
#pragma unroll
    for (int ni = 0; ni < 4; ++ni)
#pragma unroll
      for (int r = 0; r < 4; ++r) {
        float v = acc[mi][ni][r];
        size_t idx = (size_t)(row0 + wm + mi * 16 + lq * 4 + r) * N + col0 + wn + ni * 16 + lr;
        if constexpr (sizeof(OUT) == 2) C[idx] = (OUT)f2bf(v);
        else                            C[idx] = (OUT)v;
      }
}

// ---------------- RoPE + head-major reorg for Q,K (bf16 qkv input) ----------------
// Q pre-scaled by (1/sqrt(HD)) * log2(e) so softmax uses exp2 directly.
#define SCL2 0.12753224f

__global__ void rope_reorg(const u16* __restrict__ qkv, const int* __restrict__ pos,
                           u16* __restrict__ Qh, u16* __restrict__ Kh) {
  int idx = blockIdx.x * 256 + threadIdx.x;
  if (idx >= T_SEQ * NH * 64) return;
  int d = idx & 63;
  int h = (idx >> 6) & (NH - 1);
  int t = idx >> 10;
  float p = (float)pos[t];
  float inv = exp2f((float)d * -0.20762050594046932f);
  float f = p * inv;
  float s, c;
  __sincosf(f, &s, &c);

  size_t ib = (size_t)t * QKVN + h * HD + d;
  float q1 = bf2f(qkv[ib]), q2 = bf2f(qkv[ib + 64]);
  float k1 = bf2f(qkv[ib + HID]), k2 = bf2f(qkv[ib + HID + 64]);
  size_t ob = ((size_t)h * T_SEQ + t) * HD + d;
  Qh[ob]      = f2bf((q1 * c - q2 * s) * SCL2);
  Qh[ob + 64] = f2bf((q2 * c + q1 * s) * SCL2);
  Kh[ob]      = f2bf(k1 * c - k2 * s);
  Kh[ob + 64] = f2bf(k2 * c + k1 * s);
}

// ---------------- V transpose: qkv v-part bf16 -> Vt bf16 [NH][HD][T] -------------
__global__ void vtrans(const u16* __restrict__ qkv, u16* __restrict__ Vt) {
  __shared__ u16 tile[64][136];   // +8 u16 pad
  int t0 = blockIdx.x * 64;
  int h = blockIdx.y;
  int tid = threadIdx.x;
#pragma unroll
  for (int i = 0; i < 32; ++i) {
    int e = i * 256 + tid;
    int tt = e >> 7, d = e & 127;
    tile[tt][d] = qkv[(size_t)(t0 + tt) * QKVN + 2 * HID + h * HD + d];
  }
  __syncthreads();
#pragma unroll
  for (int i = 0; i < 32; ++i) {
    int e = i * 256 + tid;
    int d = e >> 6, tt = e & 63;
    Vt[((size_t)h * HD + d) * T_SEQ + t0 + tt] = tile[tt][d];
  }
}

// ---------------- causal flash attention v9: R4 skeleton + swapped QK^T ----------
// 4 waves/block, Q-tile 128 (32 rows/wave), KVB=32, plain-dbuf __syncthreads.
// S^T = mfma(K,Q): lane holds col=q(lane&15), 8 k-values -> in-register softmax:
// row-max = 7 fmax + 2 shfl; l = per-lane partial (deferred); P packed, 4x
// ds_write_b64. Rescale factors broadcast to acc layout via 8 bpermute shfls.
// K XOR-8 swizzle; V chunk-key (row>>1)&3 (8 distinct bank-quads/group); P 72B rows.
__global__ __launch_bounds__(256)
void attn_fwd(const u16* __restrict__ Qh, const u16* __restrict__ Kh,
              const u16* __restrict__ Vt, u16* __restrict__ attn) {
  __shared__ u16 Ks[2][32 * 128];   // [kv][d] 256B rows, XOR-8 swizzle
  __shared__ u16 Vs[2][128 * 32];   // [d][kv] 64B rows, key=(row>>1)&3
  __shared__ u16 Ps[4][32 * 36];    // per-wave [q][kv], 72B padded rows

  int tid = threadIdx.x;
  int wv = tid >> 6, lane = tid & 63, lr = lane & 15, lq = lane >> 4;
  // balanced decode: CU-paired blocks get bq and 31-bq
  int id = blockIdx.x;
  int h = id >> 5;
  int bq = (id < 256) ? (id & 31) : 31 - (id & 31);
  int q0 = bq * 128, wrow0 = q0 + wv * 32;
  char* PsB = (char*)&Ps[wv][0];

  // Q fragments (pre-scaled): rows wrow0 + mi*16 + lr, k = kd*32 + lq*8
  bf16x8 qf[2][4];
#pragma unroll
  for (int mi = 0; mi < 2; ++mi)
#pragma unroll
    for (int kd = 0; kd < 4; ++kd)
      qf[mi][kd] = *(const bf16x8*)
          &Qh[((size_t)h * T_SEQ + wrow0 + mi * 16 + lr) * HD + kd * 32 + lq * 8];

  f32x4 acc_o[2][8] = {};
  float m_run[2] = {-1e30f, -1e30f};
  float l_run[2] = {0.0f, 0.0f};

  auto stage = [&](int buf, int jb) {
#pragma unroll
    for (int k = 0; k < 2; ++k) {      // K tile: 512 chunks, 16/row, src pre-swz
      int c = k * 256 + tid;
      int row = c >> 4;
      int sc = (c ^ (row & 7)) & 15;
      async16(&Kh[((size_t)h * T_SEQ + jb + row) * HD + sc * 8], &Ks[buf][c * 8]);
    }
#pragma unroll
    for (int k = 0; k < 2; ++k) {      // V tile: 512 chunks, 4/row, key-swz
      int c = k * 256 + tid;
      int row = c >> 2, col = c & 3;
      int key = (row >> 1) & 3;
      async16(&Vt[((size_t)h * HD + row) * T_SEQ + jb + (col ^ key) * 8],
              &Vs[buf][c * 8]);
    }
  };

  int nt = bq * 4 + 4;
  stage(0, 0);
  __syncthreads();

  for (int j = 0; j < nt; ++j) {
    int cur = j & 1;
    int jb = j * KVB;
    if (j + 1 < nt) stage(cur ^ 1, jb + KVB);

    if (jb <= wrow0 + 31) {
      const char* KsB = (const char*)&Ks[cur][0];
      const char* VsB = (const char*)&Vs[cur][0];

      // ---- S^T = K Q^T  (swapped operands; st[kj][qi]: col=q_local=lr,
      //      row = k_local = lq*4 + r) ----
      f32x4 st[2][2] = {};
#pragma unroll
      for (int kd = 0; kd < 4; ++kd) {
#pragma unroll
        for (int kj = 0; kj < 2; ++kj) {
          int row = kj * 16 + lr;
          int byt = (row << 8) + kd * 64 + lq * 16;
          bf16x8 kf = *(const bf16x8*)(KsB + (byt ^ ((row & 7) << 4)));
#pragma unroll
          for (int qi = 0; qi < 2; ++qi)
            st[kj][qi] = __builtin_amdgcn_mfma_f32_16x16x32_bf16(
                kf, qf[qi][kd], st[kj][qi], 0, 0, 0);
        }
      }

      // ---- causal mask (wave-uniform branch; all in-lane) ----
      if (jb + KVB - 1 > wrow0) {
#pragma unroll
        for (int qi = 0; qi < 2; ++qi) {
          int qg = wrow0 + qi * 16 + lr;
#pragma unroll
          for (int kj = 0; kj < 2; ++kj)
#pragma unroll
            for (int r = 0; r < 4; ++r)
              if (jb + kj * 16 + lq * 4 + r > qg) st[kj][qi][r] = -1e30f;
        }
      }

      // ---- in-register softmax per q-column ----
      float sf[2];
#pragma unroll
      for (int qi = 0; qi < 2; ++qi) {
        float mx = fmaxf(fmaxf(fmaxf(st[0][qi][0], st[0][qi][1]),
                               fmaxf(st[0][qi][2], st[0][qi][3])),
                         fmaxf(fmaxf(st[1][qi][0], st[1][qi][1]),
                               fmaxf(st[1][qi][2], st[1][qi][3])));
        mx = fmaxf(mx, __shfl_xor(mx, 16));
        mx = fmaxf(mx, __shfl_xor(mx, 32));
        float mnew = fmaxf(m_run[qi], mx);
        sf[qi] = exp2f(m_run[qi] - mnew);
        m_run[qi] = mnew;

        float rs = 0.0f;
#pragma unroll
        for (int kj = 0; kj < 2; ++kj) {
          float p0 = exp2f(st[kj][qi][0] - mnew);
          float p1 = exp2f(st[kj][qi][1] - mnew);
          float p2 = exp2f(st[kj][qi][2] - mnew);
          float p3 = exp2f(st[kj][qi][3] - mnew);
          rs += (p0 + p1) + (p2 + p3);
          uint2 w;
          w.x = (u32)f2bf(p0) | ((u32)f2bf(p1) << 16);
          w.y = (u32)f2bf(p2) | ((u32)f2bf(p3) << 16);
          *(uint2*)(PsB + (qi * 16 + lr) * 72 + (kj * 16 + lq * 4) * 2) = w;
        }
        l_run[qi] = l_run[qi] * sf[qi] + rs;   // per-lane partial l
      }

      // ---- broadcast rescale factors to acc layout, rescale O ----
#pragma unroll
      for (int mi = 0; mi < 2; ++mi) {
        float sfb[4];
#pragma unroll
        for (int r = 0; r < 4; ++r) sfb[r] = __shfl(sf[mi], lq * 4 + r);
#pragma unroll
        for (int nd = 0; nd < 8; ++nd)
#pragma unroll
          for (int r = 0; r < 4; ++r) acc_o[mi][nd][r] *= sfb[r];
      }

      // ---- O += P V  (32 x 128, K=32) ----
#pragma unroll
      for (int mi = 0; mi < 2; ++mi) {
        bf16x8 pa = *(const bf16x8*)(PsB + (mi * 16 + lr) * 72 + lq * 16);
#pragma unroll
        for (int nd = 0; nd < 8; ++nd) {
          int vrow = nd * 16 + lr;
          bf16x8 vb = *(const bf16x8*)(VsB + vrow * 64 + ((lq ^ ((vrow >> 1) & 3)) << 4));
          acc_o[mi][nd] = __builtin_amdgcn_mfma_f32_16x16x32_bf16(
              pa, vb, acc_o[mi][nd], 0, 0, 0);
        }
      }
    }
    __syncthreads();
  }

  // epilogue: reduce per-lane partial l, broadcast to acc layout, store
#pragma unroll
  for (int mi = 0; mi < 2; ++mi) {
    float lred = l_run[mi];
    lred += __shfl_xor(lred, 16);
    lred += __shfl_xor(lred, 32);
    float rlb[4];
#pragma unroll
    for (int r = 0; r < 4; ++r) rlb[r] = 1.0f / __shfl(lred, lq * 4 + r);
#pragma unroll
    for (int r = 0; r < 4; ++r) {
      int qrow = wrow0 + mi * 16 + lq * 4 + r;
#pragma unroll
      for (int nd = 0; nd < 8; ++nd)
        attn[(size_t)qrow * HID + h * HD + nd * 16 + lr] = f2bf(acc_o[mi][nd][r] * rlb[r]);
    }
  }
}

extern "C" void kernel_launch(void* const* d_in, const int* in_sizes, int n_in,
                              void* d_out, int out_size, void* d_ws, size_t ws_size,
                              hipStream_t stream) {
  const float* hidden    = (const float*)d_in[0];
  const int*   positions = (const int*)d_in[1];
  const float* w_qkv     = (const float*)d_in[2];
  const float* w_o       = (const float*)d_in[3];
  float* out = (float*)d_out;

  char* p = (char*)d_ws;
  u16* hs_b   = (u16*)p;  p += (size_t)T_SEQ * HID * 2;
  u16* wqkvT  = (u16*)p;  p += (size_t)QKVN * HID * 2;
  u16* woT    = (u16*)p;  p += (size_t)HID * HID * 2;
  u16* qkvb   = (u16*)p;  p += (size_t)T_SEQ * QKVN * 2;
  u16* Qh     = (u16*)p;  p += (size_t)T_SEQ * HID * 2;
  u16* Kh     = (u16*)p;  p += (size_t)T_SEQ * HID * 2;
  u16* Vt     = (u16*)p;  p += (size_t)T_SEQ * HID * 2;
  u16* attn_b = (u16*)p;  p += (size_t)T_SEQ * HID * 2;

  cast_f32_bf16<<<(T_SEQ * HID / 4 + 255) / 256, 256, 0, stream>>>(hidden, hs_b, T_SEQ * HID);
  transpose_cast<<<dim3(QKVN / 64, HID / 64), 256, 0, stream>>>(w_qkv, wqkvT, HID, QKVN);
  transpose_cast<<<dim3(HID / 64, HID / 64), 256, 0, stream>>>(w_o, woT, HID, HID);
  gemm_bf16_bt<u16><<<dim3(QKVN / 128, T_SEQ / 128), 256, 0, stream>>>(hs_b, wqkvT, qkvb,
                                                                       T_SEQ, QKVN, HID);
  rope_reorg<<<(T_SEQ * NH * 64 + 255) / 256, 256, 0, stream>>>(qkvb, positions, Qh, Kh);
  vtrans<<<dim3(T_SEQ / 64, NH), 256, 0, stream>>>(qkvb, Vt);
  attn_fwd<<<512, 256, 0, stream>>>(Qh, Kh, Vt, attn_b);
  gemm_bf16_bt<float><<<dim3(HID / 128, T_SEQ / 128), 256, 0, stream>>>(attn_b, woT, out,
                                                                        T_SEQ, HID, HID);
}